// Round 3
// baseline (1258.218 us; speedup 1.0000x reference)
//
#include <hip/hip_runtime.h>
#include <hip/hip_bf16.h>
#include <math.h>

// MoE MLP: T=8192 tokens, 8 experts, top-2, HID=1024, FFN=2048 (GLU).
// Pipeline: router(fp64 acc) -> offsets -> scatter -> GEMM1(bf16 MFMA,
// fused swiglu) -> GEMM2(bf16 MFMA) -> combine (no atomics on output).

#define T_TOK 8192
#define HID   1024
#define NEXP  8
#define FFN   2048
#define MAXPAD (2 * T_TOK + NEXP * 64) /* 16896: per-expert counts padded to 64 */
#define MTILES (MAXPAD / 64)           /* 264 */

typedef __attribute__((ext_vector_type(4))) float f32x4;
typedef __attribute__((ext_vector_type(8))) short bf16x8;

static __device__ __forceinline__ unsigned short f2bf(float f) {
  // round-to-nearest-even fp32 -> bf16 (inputs finite; no NaN handling needed)
  unsigned int u = __float_as_uint(f);
  u += 0x7fffu + ((u >> 16) & 1u);
  return (unsigned short)(u >> 16);
}
static __device__ __forceinline__ float bf2f(unsigned short h) {
  return __uint_as_float(((unsigned int)h) << 16);
}

// ---------------- K1: router (fp64 accumulation), top-2, gates, counts -----
__global__ void k_router(const float* __restrict__ x, const float* __restrict__ wr,
                         int* __restrict__ tok_idx, float* __restrict__ tok_gate,
                         int* __restrict__ hdr) {
  const int lane = threadIdx.x & 63;
  const int wid  = threadIdx.x >> 6;
  const int t    = blockIdx.x * 4 + wid;
  double acc[8];
#pragma unroll
  for (int e = 0; e < 8; ++e) acc[e] = 0.0;
  const float* xr = x + (size_t)t * HID;
  for (int k = lane; k < HID; k += 64) {
    const float xv = xr[k];
    const float* wrow = wr + (size_t)k * 8;
#pragma unroll
    for (int e = 0; e < 8; ++e) acc[e] += (double)xv * (double)wrow[e];
  }
#pragma unroll
  for (int e = 0; e < 8; ++e) {
#pragma unroll
    for (int off = 32; off > 0; off >>= 1) acc[e] += __shfl_down(acc[e], off);
  }
  if (lane == 0) {
    double v0 = -1e300, v1 = -1e300;
    int i0 = 0, i1 = 0;
#pragma unroll
    for (int e = 0; e < 8; ++e) {
      const double v = acc[e];
      if (v > v0)      { v1 = v0; i1 = i0; v0 = v; i0 = e; }
      else if (v > v1) { v1 = v; i1 = e; }
    }
    const float g0 = 1.0f / (1.0f + expf((float)(v1 - v0)));
    tok_idx[2 * t]     = i0;
    tok_idx[2 * t + 1] = i1;
    tok_gate[2 * t]     = g0;
    tok_gate[2 * t + 1] = 1.0f - g0;
    atomicAdd(&hdr[i0], 1);
    atomicAdd(&hdr[i1], 1);
  }
}

// ---------------- K2: offsets (pad each expert's count to multiple of 64) --
// hdr: [0..7]=counts, [8..15]=cursor, [16..24]=off_pad, [25]=total_pad
__global__ void k_offsets(int* __restrict__ hdr) {
  int off = 0;
  for (int e = 0; e < 8; ++e) {
    hdr[16 + e] = off;
    off += (hdr[e] + 63) & ~63;
  }
  hdr[24] = off;
  hdr[25] = off;
}

// ---------------- K3: scatter tokens into per-expert buckets ---------------
__global__ void k_scatter(const int* __restrict__ tok_idx, int* __restrict__ hdr,
                          int* __restrict__ bucket_tok, int* __restrict__ rowmap) {
  const int i = blockIdx.x * 256 + threadIdx.x;
  if (i >= 2 * T_TOK) return;
  const int e = tok_idx[i];
  const int pos = atomicAdd(&hdr[8 + e], 1);
  const int r = hdr[16 + e] + pos;
  bucket_tok[r] = i >> 1;
  rowmap[i] = r;
}

// ---------------- K4: GEMM1  act = (x@w1a) * silu(x@w1g), bf16 MFMA --------
// grid: (FFN/64 n-tiles, 264 m-tiles). Block 64x64, 4 waves of 32x32.
__global__ __launch_bounds__(256) void k_gemm1(
    const float* __restrict__ x, const float* __restrict__ w1,
    const int* __restrict__ bucket_tok, const int* __restrict__ hdr,
    unsigned short* __restrict__ act) {
  const int total = hdr[25];
  const int m0 = blockIdx.y * 64;
  if (m0 >= total) return;
  int e = 0;
#pragma unroll
  for (int q = 1; q < 8; ++q) e += (m0 >= hdr[16 + q]) ? 1 : 0;
  const int j0 = blockIdx.x * 64;
  const float* w1e = w1 + (size_t)e * HID * (2 * FFN);

  __shared__ int toks[64];
  __shared__ unsigned short As[64][72]; // [m][k], stride 144B = 9*16B (aligned, bank-spread)
  __shared__ unsigned short Ba[64][72]; // [n][k] (transposed)
  __shared__ unsigned short Bg[64][72];

  const int tid = threadIdx.x;
  if (tid < 64) toks[tid] = bucket_tok[m0 + tid];
  __syncthreads();

  const int lane = tid & 63;
  const int wid  = tid >> 6;
  const int wm = (wid >> 1) << 5;
  const int wn = (wid & 1) << 5;
  const int lr = lane & 15;        // row/col within a 16-frag
  const int lk = (lane >> 4) << 3; // k base within a 32-frag

  f32x4 acc_a[2][2] = {};
  f32x4 acc_g[2][2] = {};

  for (int k0 = 0; k0 < HID; k0 += 64) {
    // stage A: 64 gathered x rows x 64 k (fp32 -> bf16)
#pragma unroll
    for (int p = 0; p < 4; ++p) {
      const int f = tid + p * 256;
      const int row = f >> 4;
      const int kq  = (f & 15) << 2;
      const float4 v = *reinterpret_cast<const float4*>(
          x + (size_t)toks[row] * HID + k0 + kq);
      ushort4 h;
      h.x = f2bf(v.x); h.y = f2bf(v.y); h.z = f2bf(v.z); h.w = f2bf(v.w);
      *reinterpret_cast<ushort4*>(&As[row][kq]) = h;
    }
    // stage Ba/Bg: w1[e][k0..][j0..] and [2048+j0..], transposed to [n][k]
#pragma unroll
    for (int p = 0; p < 4; ++p) {
      const int f = tid + p * 256;
      const int k  = f >> 4;
      const int nq = (f & 15) << 2;
      const float* src = w1e + (size_t)(k0 + k) * (2 * FFN) + j0 + nq;
      const float4 va = *reinterpret_cast<const float4*>(src);
      const float4 vg = *reinterpret_cast<const float4*>(src + FFN);
      Ba[nq + 0][k] = f2bf(va.x); Ba[nq + 1][k] = f2bf(va.y);
      Ba[nq + 2][k] = f2bf(va.z); Ba[nq + 3][k] = f2bf(va.w);
      Bg[nq + 0][k] = f2bf(vg.x); Bg[nq + 1][k] = f2bf(vg.y);
      Bg[nq + 2][k] = f2bf(vg.z); Bg[nq + 3][k] = f2bf(vg.w);
    }
    __syncthreads();
#pragma unroll
    for (int kk = 0; kk < 2; ++kk) {
      const int kb = (kk << 5) + lk;
      const bf16x8 a0  = *reinterpret_cast<const bf16x8*>(&As[wm + lr][kb]);
      const bf16x8 a1  = *reinterpret_cast<const bf16x8*>(&As[wm + 16 + lr][kb]);
      const bf16x8 ba0 = *reinterpret_cast<const bf16x8*>(&Ba[wn + lr][kb]);
      const bf16x8 ba1 = *reinterpret_cast<const bf16x8*>(&Ba[wn + 16 + lr][kb]);
      const bf16x8 bg0 = *reinterpret_cast<const bf16x8*>(&Bg[wn + lr][kb]);
      const bf16x8 bg1 = *reinterpret_cast<const bf16x8*>(&Bg[wn + 16 + lr][kb]);
      acc_a[0][0] = __builtin_amdgcn_mfma_f32_16x16x32_bf16(a0, ba0, acc_a[0][0], 0, 0, 0);
      acc_a[0][1] = __builtin_amdgcn_mfma_f32_16x16x32_bf16(a0, ba1, acc_a[0][1], 0, 0, 0);
      acc_a[1][0] = __builtin_amdgcn_mfma_f32_16x16x32_bf16(a1, ba0, acc_a[1][0], 0, 0, 0);
      acc_a[1][1] = __builtin_amdgcn_mfma_f32_16x16x32_bf16(a1, ba1, acc_a[1][1], 0, 0, 0);
      acc_g[0][0] = __builtin_amdgcn_mfma_f32_16x16x32_bf16(a0, bg0, acc_g[0][0], 0, 0, 0);
      acc_g[0][1] = __builtin_amdgcn_mfma_f32_16x16x32_bf16(a0, bg1, acc_g[0][1], 0, 0, 0);
      acc_g[1][0] = __builtin_amdgcn_mfma_f32_16x16x32_bf16(a1, bg0, acc_g[1][0], 0, 0, 0);
      acc_g[1][1] = __builtin_amdgcn_mfma_f32_16x16x32_bf16(a1, bg1, acc_g[1][1], 0, 0, 0);
    }
    __syncthreads();
  }
  // epilogue: act = a * silu(g); C-layout col=lane&15, row=(lane>>4)*4+reg
#pragma unroll
  for (int mi = 0; mi < 2; ++mi) {
#pragma unroll
    for (int ni = 0; ni < 2; ++ni) {
      const f32x4 va = acc_a[mi][ni];
      const f32x4 vg = acc_g[mi][ni];
#pragma unroll
      for (int r = 0; r < 4; ++r) {
        const int grow = m0 + wm + mi * 16 + ((lane >> 4) << 2) + r;
        const int col  = j0 + wn + ni * 16 + lr;
        const float g = vg[r];
        const float s = g / (1.0f + expf(-g));
        act[(size_t)grow * FFN + col] = f2bf(va[r] * s);
      }
    }
  }
}

// ---------------- K5: GEMM2  y = act @ w2[e], bf16 MFMA --------------------
__global__ __launch_bounds__(256) void k_gemm2(
    const unsigned short* __restrict__ act, const float* __restrict__ w2,
    const int* __restrict__ hdr, unsigned short* __restrict__ y) {
  const int total = hdr[25];
  const int m0 = blockIdx.y * 64;
  if (m0 >= total) return;
  int e = 0;
#pragma unroll
  for (int q = 1; q < 8; ++q) e += (m0 >= hdr[16 + q]) ? 1 : 0;
  const int n0 = blockIdx.x * 64;
  const float* w2e = w2 + (size_t)e * FFN * HID;

  __shared__ unsigned short As[64][72];
  __shared__ unsigned short Bs[64][72];

  const int tid = threadIdx.x;
  const int lane = tid & 63;
  const int wid  = tid >> 6;
  const int wm = (wid >> 1) << 5;
  const int wn = (wid & 1) << 5;
  const int lr = lane & 15;
  const int lk = (lane >> 4) << 3;

  f32x4 acc[2][2] = {};

  for (int k0 = 0; k0 < FFN; k0 += 64) {
    // stage A: 64 act rows x 64 k (already bf16, rows contiguous in bucket space)
#pragma unroll
    for (int p = 0; p < 2; ++p) {
      const int f = tid + p * 256;
      const int row = f >> 3;
      const int ko  = (f & 7) << 3;
      const float4 v = *reinterpret_cast<const float4*>(
          act + (size_t)(m0 + row) * FFN + k0 + ko);
      *reinterpret_cast<float4*>(&As[row][ko]) = v;
    }
    // stage B: w2[e][k0..][n0..] fp32 -> bf16, transposed to [n][k]
#pragma unroll
    for (int p = 0; p < 4; ++p) {
      const int f = tid + p * 256;
      const int k  = f >> 4;
      const int nq = (f & 15) << 2;
      const float4 v = *reinterpret_cast<const float4*>(
          w2e + (size_t)(k0 + k) * HID + n0 + nq);
      Bs[nq + 0][k] = f2bf(v.x); Bs[nq + 1][k] = f2bf(v.y);
      Bs[nq + 2][k] = f2bf(v.z); Bs[nq + 3][k] = f2bf(v.w);
    }
    __syncthreads();
#pragma unroll
    for (int kk = 0; kk < 2; ++kk) {
      const int kb = (kk << 5) + lk;
      const bf16x8 a0 = *reinterpret_cast<const bf16x8*>(&As[wm + lr][kb]);
      const bf16x8 a1 = *reinterpret_cast<const bf16x8*>(&As[wm + 16 + lr][kb]);
      const bf16x8 b0 = *reinterpret_cast<const bf16x8*>(&Bs[wn + lr][kb]);
      const bf16x8 b1 = *reinterpret_cast<const bf16x8*>(&Bs[wn + 16 + lr][kb]);
      acc[0][0] = __builtin_amdgcn_mfma_f32_16x16x32_bf16(a0, b0, acc[0][0], 0, 0, 0);
      acc[0][1] = __builtin_amdgcn_mfma_f32_16x16x32_bf16(a0, b1, acc[0][1], 0, 0, 0);
      acc[1][0] = __builtin_amdgcn_mfma_f32_16x16x32_bf16(a1, b0, acc[1][0], 0, 0, 0);
      acc[1][1] = __builtin_amdgcn_mfma_f32_16x16x32_bf16(a1, b1, acc[1][1], 0, 0, 0);
    }
    __syncthreads();
  }
#pragma unroll
  for (int mi = 0; mi < 2; ++mi) {
#pragma unroll
    for (int ni = 0; ni < 2; ++ni) {
#pragma unroll
      for (int r = 0; r < 4; ++r) {
        const int grow = m0 + wm + mi * 16 + ((lane >> 4) << 2) + r;
        const int col  = n0 + wn + ni * 16 + lr;
        y[(size_t)grow * HID + col] = f2bf(acc[mi][ni][r]);
      }
    }
  }
}

// ---------------- K6: combine  out[t] = g0*y[r0] + g1*y[r1] ----------------
__global__ void k_combine(const unsigned short* __restrict__ y,
                          const int* __restrict__ rowmap,
                          const float* __restrict__ tok_gate,
                          float* __restrict__ out) {
  const int t = blockIdx.x;
  const int c = threadIdx.x << 2;
  const int r0 = rowmap[2 * t], r1 = rowmap[2 * t + 1];
  const float g0 = tok_gate[2 * t], g1 = tok_gate[2 * t + 1];
  const ushort4 a = *reinterpret_cast<const ushort4*>(y + (size_t)r0 * HID + c);
  const ushort4 b = *reinterpret_cast<const ushort4*>(y + (size_t)r1 * HID + c);
  float4 o;
  o.x = g0 * bf2f(a.x) + g1 * bf2f(b.x);
  o.y = g0 * bf2f(a.y) + g1 * bf2f(b.y);
  o.z = g0 * bf2f(a.z) + g1 * bf2f(b.z);
  o.w = g0 * bf2f(a.w) + g1 * bf2f(b.w);
  *reinterpret_cast<float4*>(out + (size_t)t * HID + c) = o;
}

extern "C" void kernel_launch(void* const* d_in, const int* in_sizes, int n_in,
                              void* d_out, int out_size, void* d_ws, size_t ws_size,
                              hipStream_t stream) {
  const float* x  = (const float*)d_in[0]; // [8192][1024]
  const float* wr = (const float*)d_in[1]; // [1024][8]
  const float* w1 = (const float*)d_in[2]; // [8][1024][4096]
  const float* w2 = (const float*)d_in[3]; // [8][2048][1024]
  float* out = (float*)d_out;              // [8192][1024] fp32

  // ws layout (needs ~104 MB):
  // [0,256)        header: counts[8], cursor[8], off_pad[9], total
  // [256, +64K)    tok_idx  int[16384]
  // [.., +64K)     tok_gate float[16384]
  // [.., +64K)     rowmap   int[16384]
  // [.., +66K)     bucket_tok int[MAXPAD]
  // [264448, ..)   act bf16 [MAXPAD][2048]  (69.2 MB)
  // then           y   bf16 [MAXPAD][1024]  (34.6 MB)
  char* w = (char*)d_ws;
  int*   hdr        = (int*)w;
  int*   tok_idx    = (int*)(w + 256);
  float* tok_gate   = (float*)(w + 256 + 65536);
  int*   rowmap     = (int*)(w + 256 + 2 * 65536);
  int*   bucket_tok = (int*)(w + 256 + 3 * 65536);
  unsigned short* act = (unsigned short*)(w + 264448);
  unsigned short* yb  = act + (size_t)MAXPAD * FFN;

  hipMemsetAsync(hdr, 0, 256, stream);
  hipMemsetAsync(bucket_tok, 0, MAXPAD * sizeof(int), stream); // pad rows -> token 0

  k_router<<<T_TOK / 4, 256, 0, stream>>>(x, wr, tok_idx, tok_gate, hdr);
  k_offsets<<<1, 1, 0, stream>>>(hdr);
  k_scatter<<<(2 * T_TOK) / 256, 256, 0, stream>>>(tok_idx, hdr, bucket_tok, rowmap);
  k_gemm1<<<dim3(FFN / 64, MTILES), 256, 0, stream>>>(x, w1, bucket_tok, hdr, act);
  k_gemm2<<<dim3(HID / 64, MTILES), 256, 0, stream>>>(act, w2, hdr, yb);
  k_combine<<<T_TOK, 256, 0, stream>>>(yb, rowmap, tok_gate, out);
}

// Round 4
// 702.752 us; speedup vs baseline: 1.7904x; 1.7904x over previous
//
#include <hip/hip_runtime.h>
#include <hip/hip_bf16.h>
#include <math.h>

// MoE MLP: T=8192 tokens, 8 experts, top-2, HID=1024, FFN=2048 (GLU).
// R3: bf16 pre-convert (+ weight transpose to [n][k]) -> m97-structure GEMMs:
// global_load_lds width=16, linear LDS + XOR swizzle via pre-swizzled source,
// 128x128 tiles, fused swiglu in GEMM1 epilogue.

#define T_TOK 8192
#define HID   1024
#define NEXP  8
#define FFN   2048
#define PADU  128                       /* per-expert pad unit = m-tile */
#define MAXPAD (2 * T_TOK + NEXP * PADU) /* 17408 */
#define MT     (MAXPAD / 128)            /* 136 m-tiles */

typedef __attribute__((ext_vector_type(4))) float f32x4;
typedef __attribute__((ext_vector_type(8))) short bf16x8;

static __device__ __forceinline__ unsigned short f2bf(float f) {
  unsigned int u = __float_as_uint(f);
  u += 0x7fffu + ((u >> 16) & 1u);
  return (unsigned short)(u >> 16);
}
static __device__ __forceinline__ float bf2f(unsigned short h) {
  return __uint_as_float(((unsigned int)h) << 16);
}

// global -> LDS direct DMA, 16B per lane; LDS dest = wave-uniform base + lane*16
#define GLDS16(gsrc, ldst)                                                  \
  __builtin_amdgcn_global_load_lds(                                        \
      (const __attribute__((address_space(1))) void*)(gsrc),               \
      (__attribute__((address_space(3))) void*)(ldst), 16, 0, 0)

// ---------------- K1: router (fp64 accumulation), top-2, gates, counts -----
__global__ void k_router(const float* __restrict__ x, const float* __restrict__ wr,
                         int* __restrict__ tok_idx, float* __restrict__ tok_gate,
                         int* __restrict__ hdr) {
  const int lane = threadIdx.x & 63;
  const int wid  = threadIdx.x >> 6;
  const int t    = blockIdx.x * 4 + wid;
  double acc[8];
#pragma unroll
  for (int e = 0; e < 8; ++e) acc[e] = 0.0;
  const float* xr = x + (size_t)t * HID;
  for (int k = lane; k < HID; k += 64) {
    const float xv = xr[k];
    const float* wrow = wr + (size_t)k * 8;
#pragma unroll
    for (int e = 0; e < 8; ++e) acc[e] += (double)xv * (double)wrow[e];
  }
#pragma unroll
  for (int e = 0; e < 8; ++e) {
#pragma unroll
    for (int off = 32; off > 0; off >>= 1) acc[e] += __shfl_down(acc[e], off);
  }
  if (lane == 0) {
    double v0 = -1e300, v1 = -1e300;
    int i0 = 0, i1 = 0;
#pragma unroll
    for (int e = 0; e < 8; ++e) {
      const double v = acc[e];
      if (v > v0)      { v1 = v0; i1 = i0; v0 = v; i0 = e; }
      else if (v > v1) { v1 = v; i1 = e; }
    }
    const float g0 = 1.0f / (1.0f + expf((float)(v1 - v0)));
    tok_idx[2 * t]     = i0;
    tok_idx[2 * t + 1] = i1;
    tok_gate[2 * t]     = g0;
    tok_gate[2 * t + 1] = 1.0f - g0;
    atomicAdd(&hdr[i0], 1);
    atomicAdd(&hdr[i1], 1);
  }
}

// ---------------- K2: offsets (pad each expert's count to multiple of 128) -
// hdr: [0..7]=counts, [8..15]=cursor, [16..23]=off_pad, [24]=end, [25]=total
__global__ void k_offsets(int* __restrict__ hdr) {
  int off = 0;
  for (int e = 0; e < 8; ++e) {
    hdr[16 + e] = off;
    off += (hdr[e] + PADU - 1) & ~(PADU - 1);
  }
  hdr[24] = off;
  hdr[25] = off;
}

// ---------------- K3: scatter tokens into per-expert buckets ---------------
__global__ void k_scatter(const int* __restrict__ tok_idx, int* __restrict__ hdr,
                          int* __restrict__ bucket_tok, int* __restrict__ rowmap) {
  const int i = blockIdx.x * 256 + threadIdx.x;
  if (i >= 2 * T_TOK) return;
  const int e = tok_idx[i];
  const int pos = atomicAdd(&hdr[8 + e], 1);
  const int r = hdr[16 + e] + pos;
  bucket_tok[r] = i >> 1;
  rowmap[i] = r;
}

// ---------------- K4: x fp32 -> bf16 ---------------------------------------
__global__ void k_cvt_x(const float* __restrict__ x, unsigned short* __restrict__ xb) {
  const int i = blockIdx.x * 256 + threadIdx.x; // over 2,097,152 float4s
  const float4 v = reinterpret_cast<const float4*>(x)[i];
  ushort4 h;
  h.x = f2bf(v.x); h.y = f2bf(v.y); h.z = f2bf(v.z); h.w = f2bf(v.w);
  reinterpret_cast<ushort4*>(xb)[i] = h;
}

// ---------------- K5: convert+transpose  src[e][R][C] f32 -> dst[e][C][R] bf16
__global__ void k_cvtT(const float* __restrict__ src, unsigned short* __restrict__ dst,
                       int R, int C) {
  const int e  = blockIdx.z;
  const int c0 = blockIdx.x * 64;
  const int r0 = blockIdx.y * 64;
  __shared__ unsigned short t[64][68];
  const int tid = threadIdx.x;
  const float* s = src + (size_t)e * R * C;
  unsigned short* d = dst + (size_t)e * R * C;
#pragma unroll
  for (int p = 0; p < 4; ++p) {
    const int idx = tid + p * 256;
    const int r  = idx >> 4;
    const int c4 = (idx & 15) << 2;
    const float4 v = *reinterpret_cast<const float4*>(s + (size_t)(r0 + r) * C + c0 + c4);
    t[c4 + 0][r] = f2bf(v.x); t[c4 + 1][r] = f2bf(v.y);
    t[c4 + 2][r] = f2bf(v.z); t[c4 + 3][r] = f2bf(v.w);
  }
  __syncthreads();
#pragma unroll
  for (int p = 0; p < 4; ++p) {
    const int idx = tid + p * 256;
    const int c  = idx >> 4;
    const int r4 = (idx & 15) << 2;
    ushort4 v;
    v.x = t[c][r4]; v.y = t[c][r4 + 1]; v.z = t[c][r4 + 2]; v.w = t[c][r4 + 3];
    *reinterpret_cast<ushort4*>(d + (size_t)(c0 + c) * R + r0 + r4) = v;
  }
}

// ---------------- K6: GEMM1  act = (x@w1a) * silu(x@w1g) -------------------
// 128m x 128n tile (per half), BK=64, 4 waves in 2x2, each wave 64x64 out.
// LDS linear + XOR swizzle (byte ^= (row&7)<<4) applied via pre-swizzled
// global source for global_load_lds (rule 21), and on the ds_read address.
__global__ __launch_bounds__(256) void k_gemm1(
    const unsigned short* __restrict__ xb, const unsigned short* __restrict__ w1t,
    const int* __restrict__ bucket_tok, const int* __restrict__ hdr,
    unsigned short* __restrict__ act) {
  const int total = hdr[25];
  const int m0 = blockIdx.y * 128;
  if (m0 >= total) return;
  int e = 0;
#pragma unroll
  for (int q = 1; q < 8; ++q) e += (m0 >= hdr[16 + q]) ? 1 : 0;
  const int j0 = blockIdx.x * 128;
  const unsigned short* w1e = w1t + (size_t)e * 4096 * 1024; // [n=4096][k=1024]

  __shared__ __align__(16) unsigned short As[128 * 64];
  __shared__ __align__(16) unsigned short Ba[128 * 64];
  __shared__ __align__(16) unsigned short Bg[128 * 64];

  const int tid  = threadIdx.x;
  const int lane = tid & 63;
  const int w    = tid >> 6;
  const int wr   = (w >> 1) * 64;
  const int wc   = (w & 1) * 64;

  // staging: round j writes LDS bytes [w*4096 + j*1024 + lane*16); row = s>>7
  const int srow0 = w * 32 + (lane >> 3);
  const int cswz  = ((lane & 7) ^ ((lane >> 3) & 7)) << 3; // swizzled col (elems)

  int aoff[4], boff[4];
#pragma unroll
  for (int j = 0; j < 4; ++j) {
    const int row = srow0 + j * 8;
    aoff[j] = bucket_tok[m0 + row] * 1024 + cswz;
    boff[j] = (j0 + row) * 1024 + cswz;
  }

  f32x4 acc_a[4][4] = {};
  f32x4 acc_g[4][4] = {};

  const int lr = lane & 15;
  const int qk = lane >> 4;

  for (int k0 = 0; k0 < 1024; k0 += 64) {
#pragma unroll
    for (int j = 0; j < 4; ++j) {
      const int lo = w * 4096 + j * 1024;
      GLDS16(xb + aoff[j] + k0, (char*)As + lo);
      GLDS16(w1e + boff[j] + k0, (char*)Ba + lo);
      GLDS16(w1e + 2048 * 1024 + boff[j] + k0, (char*)Bg + lo);
    }
    __syncthreads();
#pragma unroll
    for (int kk = 0; kk < 2; ++kk) {
      bf16x8 af[4], baf[4], bgf[4];
#pragma unroll
      for (int i = 0; i < 4; ++i) {
        const int ra = wr + i * 16 + lr;
        const int ka = (kk * 64 + qk * 16) ^ ((ra & 7) << 4);
        af[i] = *reinterpret_cast<const bf16x8*>((const char*)As + ra * 128 + ka);
        const int rb = wc + i * 16 + lr;
        const int kb = (kk * 64 + qk * 16) ^ ((rb & 7) << 4);
        baf[i] = *reinterpret_cast<const bf16x8*>((const char*)Ba + rb * 128 + kb);
        bgf[i] = *reinterpret_cast<const bf16x8*>((const char*)Bg + rb * 128 + kb);
      }
#pragma unroll
      for (int mi = 0; mi < 4; ++mi)
#pragma unroll
        for (int ni = 0; ni < 4; ++ni) {
          acc_a[mi][ni] = __builtin_amdgcn_mfma_f32_16x16x32_bf16(af[mi], baf[ni], acc_a[mi][ni], 0, 0, 0);
          acc_g[mi][ni] = __builtin_amdgcn_mfma_f32_16x16x32_bf16(af[mi], bgf[ni], acc_g[mi][ni], 0, 0, 0);
        }
    }
    __syncthreads();
  }
  // epilogue: act = a * silu(g); C layout col=lane&15, row=(lane>>4)*4+reg
  const int orow = (lane >> 4) << 2;
  const int ocol = lane & 15;
#pragma unroll
  for (int mi = 0; mi < 4; ++mi)
#pragma unroll
    for (int ni = 0; ni < 4; ++ni) {
#pragma unroll
      for (int r = 0; r < 4; ++r) {
        const float a = acc_a[mi][ni][r];
        const float g = acc_g[mi][ni][r];
        const float v = a * (g / (1.0f + expf(-g)));
        const int gm = m0 + wr + mi * 16 + orow + r;
        const int gc = j0 + wc + ni * 16 + ocol;
        act[(size_t)gm * FFN + gc] = f2bf(v);
      }
    }
}

// ---------------- K7: GEMM2  y = act @ w2[e] -------------------------------
__global__ __launch_bounds__(256) void k_gemm2(
    const unsigned short* __restrict__ act, const unsigned short* __restrict__ w2t,
    const int* __restrict__ hdr, unsigned short* __restrict__ y) {
  const int total = hdr[25];
  const int m0 = blockIdx.y * 128;
  if (m0 >= total) return;
  int e = 0;
#pragma unroll
  for (int q = 1; q < 8; ++q) e += (m0 >= hdr[16 + q]) ? 1 : 0;
  const int n0 = blockIdx.x * 128;
  const unsigned short* w2e = w2t + (size_t)e * 1024 * 2048; // [n=1024][k=2048]

  __shared__ __align__(16) unsigned short As[128 * 64];
  __shared__ __align__(16) unsigned short Bs[128 * 64];

  const int tid  = threadIdx.x;
  const int lane = tid & 63;
  const int w    = tid >> 6;
  const int wr   = (w >> 1) * 64;
  const int wc   = (w & 1) * 64;

  const int srow0 = w * 32 + (lane >> 3);
  const int cswz  = ((lane & 7) ^ ((lane >> 3) & 7)) << 3;

  int aoff[4], boff[4];
#pragma unroll
  for (int j = 0; j < 4; ++j) {
    const int row = srow0 + j * 8;
    aoff[j] = (m0 + row) * FFN + cswz;
    boff[j] = (n0 + row) * FFN + cswz;
  }

  f32x4 acc[4][4] = {};
  const int lr = lane & 15;
  const int qk = lane >> 4;

  for (int k0 = 0; k0 < FFN; k0 += 64) {
#pragma unroll
    for (int j = 0; j < 4; ++j) {
      const int lo = w * 4096 + j * 1024;
      GLDS16(act + aoff[j] + k0, (char*)As + lo);
      GLDS16(w2e + boff[j] + k0, (char*)Bs + lo);
    }
    __syncthreads();
#pragma unroll
    for (int kk = 0; kk < 2; ++kk) {
      bf16x8 af[4], bf[4];
#pragma unroll
      for (int i = 0; i < 4; ++i) {
        const int ra = wr + i * 16 + lr;
        const int ka = (kk * 64 + qk * 16) ^ ((ra & 7) << 4);
        af[i] = *reinterpret_cast<const bf16x8*>((const char*)As + ra * 128 + ka);
        const int rb = wc + i * 16 + lr;
        const int kb = (kk * 64 + qk * 16) ^ ((rb & 7) << 4);
        bf[i] = *reinterpret_cast<const bf16x8*>((const char*)Bs + rb * 128 + kb);
      }
#pragma unroll
      for (int mi = 0; mi < 4; ++mi)
#pragma unroll
        for (int ni = 0; ni < 4; ++ni)
          acc[mi][ni] = __builtin_amdgcn_mfma_f32_16x16x32_bf16(af[mi], bf[ni], acc[mi][ni], 0, 0, 0);
    }
    __syncthreads();
  }
  const int orow = (lane >> 4) << 2;
  const int ocol = lane & 15;
#pragma unroll
  for (int mi = 0; mi < 4; ++mi)
#pragma unroll
    for (int ni = 0; ni < 4; ++ni)
#pragma unroll
      for (int r = 0; r < 4; ++r) {
        const int gm = m0 + wr + mi * 16 + orow + r;
        const int gc = n0 + wc + ni * 16 + ocol;
        y[(size_t)gm * HID + gc] = f2bf(acc[mi][ni][r]);
      }
}

// ---------------- K8: combine  out[t] = g0*y[r0] + g1*y[r1] ----------------
__global__ void k_combine(const unsigned short* __restrict__ y,
                          const int* __restrict__ rowmap,
                          const float* __restrict__ tok_gate,
                          float* __restrict__ out) {
  const int t = blockIdx.x;
  const int c = threadIdx.x << 2;
  const int r0 = rowmap[2 * t], r1 = rowmap[2 * t + 1];
  const float g0 = tok_gate[2 * t], g1 = tok_gate[2 * t + 1];
  const ushort4 a = *reinterpret_cast<const ushort4*>(y + (size_t)r0 * HID + c);
  const ushort4 b = *reinterpret_cast<const ushort4*>(y + (size_t)r1 * HID + c);
  float4 o;
  o.x = g0 * bf2f(a.x) + g1 * bf2f(b.x);
  o.y = g0 * bf2f(a.y) + g1 * bf2f(b.y);
  o.z = g0 * bf2f(a.z) + g1 * bf2f(b.z);
  o.w = g0 * bf2f(a.w) + g1 * bf2f(b.w);
  *reinterpret_cast<float4*>(out + (size_t)t * HID + c) = o;
}

extern "C" void kernel_launch(void* const* d_in, const int* in_sizes, int n_in,
                              void* d_out, int out_size, void* d_ws, size_t ws_size,
                              hipStream_t stream) {
  const float* x  = (const float*)d_in[0]; // [8192][1024]
  const float* wr = (const float*)d_in[1]; // [1024][8]
  const float* w1 = (const float*)d_in[2]; // [8][1024][4096]
  const float* w2 = (const float*)d_in[3]; // [8][2048][1024]
  float* out = (float*)d_out;              // [8192][1024] fp32

  // ws layout (~156 MB), region1 (xb+w1t) is overlaid by (w2t+y) after gemm1:
  //   0        hdr (1 KB)
  //   1K       tok_idx int[16384]
  //   +64K     tok_gate float[16384]
  //   +64K     rowmap int[16384]
  //   +64K     bucket_tok int[17408]
  //   512K     region1 (83.9 MB): phaseA = xb(16.8) + w1t(67.1)
  //                                phaseB = w2t(33.6) + y(35.7)
  //   512K+83.9M  act bf16 [17408][2048] (71.3 MB)
  char* w = (char*)d_ws;
  int*   hdr        = (int*)w;
  int*   tok_idx    = (int*)(w + 1024);
  float* tok_gate   = (float*)(w + 1024 + 65536);
  int*   rowmap     = (int*)(w + 1024 + 2 * 65536);
  int*   bucket_tok = (int*)(w + 1024 + 3 * 65536);
  const size_t R1 = 524288;
  unsigned short* xb  = (unsigned short*)(w + R1);
  unsigned short* w1t = (unsigned short*)(w + R1 + 16777216);
  unsigned short* w2t = (unsigned short*)(w + R1);             // overlay
  unsigned short* yb  = (unsigned short*)(w + R1 + 33554432);  // overlay
  unsigned short* act = (unsigned short*)(w + R1 + 83886080);

  hipMemsetAsync(hdr, 0, 1024, stream);
  hipMemsetAsync(bucket_tok, 0, MAXPAD * sizeof(int), stream); // pad rows -> token 0

  k_router<<<T_TOK / 4, 256, 0, stream>>>(x, wr, tok_idx, tok_gate, hdr);
  k_offsets<<<1, 1, 0, stream>>>(hdr);
  k_scatter<<<(2 * T_TOK) / 256, 256, 0, stream>>>(tok_idx, hdr, bucket_tok, rowmap);
  k_cvt_x<<<(T_TOK * HID / 4) / 256, 256, 0, stream>>>(x, xb);
  k_cvtT<<<dim3(4096 / 64, 1024 / 64, 8), 256, 0, stream>>>(w1, w1t, 1024, 4096);
  k_gemm1<<<dim3(FFN / 128, MT), 256, 0, stream>>>(xb, w1t, bucket_tok, hdr, act);
  k_cvtT<<<dim3(1024 / 64, 2048 / 64, 8), 256, 0, stream>>>(w2, w2t, 2048, 1024);
  k_gemm2<<<dim3(HID / 128, MT), 256, 0, stream>>>(act, w2t, hdr, yb);
  k_combine<<<T_TOK, 256, 0, stream>>>(yb, rowmap, tok_gate, out);
}

// Round 6
// 617.465 us; speedup vs baseline: 2.0377x; 1.1381x over previous
//
#include <hip/hip_runtime.h>
#include <hip/hip_bf16.h>
#include <math.h>

// MoE MLP: T=8192 tokens, 8 experts, top-2, HID=1024, FFN=2048 (GLU).
// R6: verified-safe T3 "minimum 2-phase" pipeline (m248v2 recipe):
// double-buffered LDS, STAGE(t+1) issued BEFORE compute(t), one
// __syncthreads() (full drain) per K-step. gemm1 fuses swiglu via
// 16-interleaved w1 columns; XOR swizzle via pre-swizzled global source.

#define T_TOK 8192
#define HID   1024
#define NEXP  8
#define FFN   2048
#define PADU  128
#define MAXPAD (2 * T_TOK + NEXP * PADU) /* 17408 */
#define MT1    (MAXPAD / 128)            /* 136 m-tiles */

typedef __attribute__((ext_vector_type(4))) float f32x4;
typedef __attribute__((ext_vector_type(8))) short bf16x8;
typedef __attribute__((ext_vector_type(8))) unsigned short u16x8;

static __device__ __forceinline__ unsigned short f2bf(float f) {
  unsigned int u = __float_as_uint(f);
  u += 0x7fffu + ((u >> 16) & 1u);
  return (unsigned short)(u >> 16);
}
static __device__ __forceinline__ float bf2f(unsigned short h) {
  return __uint_as_float(((unsigned int)h) << 16);
}

#define GLDS16(gsrc, ldst)                                                  \
  __builtin_amdgcn_global_load_lds(                                        \
      (const __attribute__((address_space(1))) void*)(gsrc),               \
      (__attribute__((address_space(3))) void*)(ldst), 16, 0, 0)

// ---------------- K1: router (fp64 accumulation), top-2, gates, counts -----
__global__ void k_router(const float* __restrict__ x, const float* __restrict__ wr,
                         int* __restrict__ tok_idx, float* __restrict__ tok_gate,
                         int* __restrict__ hdr) {
  const int lane = threadIdx.x & 63;
  const int wid  = threadIdx.x >> 6;
  const int t    = blockIdx.x * 4 + wid;
  double acc[8];
#pragma unroll
  for (int e = 0; e < 8; ++e) acc[e] = 0.0;
  const float* xr = x + (size_t)t * HID;
  for (int k = lane; k < HID; k += 64) {
    const float xv = xr[k];
    const float* wrow = wr + (size_t)k * 8;
#pragma unroll
    for (int e = 0; e < 8; ++e) acc[e] += (double)xv * (double)wrow[e];
  }
#pragma unroll
  for (int e = 0; e < 8; ++e) {
#pragma unroll
    for (int off = 32; off > 0; off >>= 1) acc[e] += __shfl_down(acc[e], off);
  }
  if (lane == 0) {
    double v0 = -1e300, v1 = -1e300;
    int i0 = 0, i1 = 0;
#pragma unroll
    for (int e = 0; e < 8; ++e) {
      const double v = acc[e];
      if (v > v0)      { v1 = v0; i1 = i0; v0 = v; i0 = e; }
      else if (v > v1) { v1 = v; i1 = e; }
    }
    const float g0 = 1.0f / (1.0f + expf((float)(v1 - v0)));
    tok_idx[2 * t]     = i0;
    tok_idx[2 * t + 1] = i1;
    tok_gate[2 * t]     = g0;
    tok_gate[2 * t + 1] = 1.0f - g0;
    atomicAdd(&hdr[i0], 1);
    atomicAdd(&hdr[i1], 1);
  }
}

// ---------------- K2: offsets (pad each expert's count to multiple of 128) -
__global__ void k_offsets(int* __restrict__ hdr) {
  int off = 0;
  for (int e = 0; e < 8; ++e) {
    hdr[16 + e] = off;
    off += (hdr[e] + PADU - 1) & ~(PADU - 1);
  }
  hdr[24] = off;
  hdr[25] = off;
}

// ---------------- K3: scatter tokens into per-expert buckets ---------------
__global__ void k_scatter(const int* __restrict__ tok_idx, int* __restrict__ hdr,
                          int* __restrict__ bucket_tok, int* __restrict__ rowmap) {
  const int i = blockIdx.x * 256 + threadIdx.x;
  if (i >= 2 * T_TOK) return;
  const int e = tok_idx[i];
  const int pos = atomicAdd(&hdr[8 + e], 1);
  const int r = hdr[16 + e] + pos;
  bucket_tok[r] = i >> 1;
  rowmap[i] = r;
}

// ---------------- K4: x fp32 -> bf16 ---------------------------------------
__global__ void k_cvt_x(const float* __restrict__ x, unsigned short* __restrict__ xb) {
  const int i = blockIdx.x * 256 + threadIdx.x;
  const float4 v = reinterpret_cast<const float4*>(x)[i];
  ushort4 h;
  h.x = f2bf(v.x); h.y = f2bf(v.y); h.z = f2bf(v.z); h.w = f2bf(v.w);
  reinterpret_cast<ushort4*>(xb)[i] = h;
}

// ---------------- K5: convert+transpose src[e][R][C] f32 -> dst[e][map(c)][R]
// ilv=1: c -> interleave16(a,g) row for fused-swiglu gemm1 B operand.
__global__ void k_cvtT(const float* __restrict__ src, unsigned short* __restrict__ dst,
                       int R, int C, int ilv) {
  const int e  = blockIdx.z;
  const int c0 = blockIdx.x * 64;
  const int r0 = blockIdx.y * 64;
  __shared__ unsigned short t[64][72];
  const int tid = threadIdx.x;
  const float* s = src + (size_t)e * R * C;
  unsigned short* d = dst + (size_t)e * R * C;
#pragma unroll
  for (int p = 0; p < 4; ++p) {
    const int idx = tid + p * 256;
    const int r  = idx >> 4;
    const int c4 = (idx & 15) << 2;
    const float4 v = *reinterpret_cast<const float4*>(s + (size_t)(r0 + r) * C + c0 + c4);
    t[c4 + 0][r] = f2bf(v.x); t[c4 + 1][r] = f2bf(v.y);
    t[c4 + 2][r] = f2bf(v.z); t[c4 + 3][r] = f2bf(v.w);
  }
  __syncthreads();
#pragma unroll
  for (int p = 0; p < 2; ++p) {
    const int idx = tid + p * 256;  // 0..511
    const int c  = idx >> 3;
    const int r8 = (idx & 7) << 3;
    u16x8 v;
#pragma unroll
    for (int i = 0; i < 8; ++i) v[i] = t[c][r8 + i];
    const int n = c0 + c;
    int row = n;
    if (ilv) {
      const int j = n & (FFN - 1);
      const int half = n >> 11;
      row = ((j >> 4) << 5) + (half << 4) + (j & 15);
    }
    *reinterpret_cast<u16x8*>(d + (size_t)row * R + r0 + r8) = v;
  }
}

// ---------------- K6: GEMM1  act = (x@w1a) * silu(x@w1g) -------------------
// BM=128 x BN=256(interleaved a/g), BK=64, 8 waves (2M x 4N), wave out 64x64.
// Double-buffered LDS; STAGE(t+1) before compute(t); __syncthreads per step.
__global__ __launch_bounds__(512, 2) void k_gemm1(
    const unsigned short* __restrict__ xb, const unsigned short* __restrict__ w1i,
    const int* __restrict__ bucket_tok, const int* __restrict__ hdr,
    unsigned short* __restrict__ act) {
  const int total = hdr[25];
  const int m0 = blockIdx.y * 128;
  if (m0 >= total) return;
  int e = 0;
#pragma unroll
  for (int q = 1; q < 8; ++q) e += (m0 >= hdr[16 + q]) ? 1 : 0;
  const int bx = blockIdx.x;  // 16 tiles of 256 interleaved cols
  const unsigned short* w1e = w1i + (size_t)e * 4096 * 1024;

  __shared__ __align__(16) char Lds[2 * 49152]; // 96 KB: 2 x (A 16K + B 32K)

  const int tid  = threadIdx.x;
  const int lane = tid & 63;
  const int w    = tid >> 6;
  const int wrow = (w >> 2) * 64;
  const int wcol = (w & 3) * 64;
  const int lr   = lane & 15;
  const int qk16 = (lane >> 4) << 4;
  const int ldsw = w * 1024;  // wave-uniform base within each 8KB stage round

  const int srow = tid >> 3;                         // 0..63
  const int cswz = (((tid & 7) ^ (srow & 7)) << 3);  // pre-swizzled k offset
  const int aoffA0 = bucket_tok[m0 + srow] * 1024 + cswz;
  const int aoffA1 = bucket_tok[m0 + 64 + srow] * 1024 + cswz;
  const int boffB0 = (bx * 256 + srow) * 1024 + cswz;

  f32x4 acc[4][4] = {};

#define G1_STAGE(base, kt) do {                                             \
    const unsigned short* xs = xb + (kt) * 64;                              \
    const unsigned short* ws = w1e + (kt) * 64;                             \
    GLDS16(xs + aoffA0,           Lds + (base) + ldsw);                     \
    GLDS16(xs + aoffA1,           Lds + (base) + 8192 + ldsw);              \
    GLDS16(ws + boffB0,           Lds + (base) + 16384 + ldsw);             \
    GLDS16(ws + boffB0 + 65536,   Lds + (base) + 24576 + ldsw);             \
    GLDS16(ws + boffB0 + 131072,  Lds + (base) + 32768 + ldsw);             \
    GLDS16(ws + boffB0 + 196608,  Lds + (base) + 40960 + ldsw);             \
  } while (0)

  G1_STAGE(0, 0);
  __syncthreads();  // tile 0 resident

  for (int t = 0; t < 16; ++t) {
    if (t + 1 < 16) G1_STAGE(((t + 1) & 1) * 49152, t + 1); // prefetch next
    {
      const char* Ab = (const char*)Lds + (t & 1) * 49152;
      const char* Bb = Ab + 16384;
#pragma unroll
      for (int kk = 0; kk < 2; ++kk) {
        bf16x8 af[4], bv[4];
#pragma unroll
        for (int i = 0; i < 4; ++i) {
          const int ra = wrow + i * 16 + lr;
          af[i] = *reinterpret_cast<const bf16x8*>(Ab + ra * 128 + ((kk * 64 + qk16) ^ ((ra & 7) << 4)));
          const int rb = wcol + i * 16 + lr;
          bv[i] = *reinterpret_cast<const bf16x8*>(Bb + rb * 128 + ((kk * 64 + qk16) ^ ((rb & 7) << 4)));
        }
        __builtin_amdgcn_s_setprio(1);
#pragma unroll
        for (int mi = 0; mi < 4; ++mi)
#pragma unroll
          for (int ni = 0; ni < 4; ++ni)
            acc[mi][ni] = __builtin_amdgcn_mfma_f32_16x16x32_bf16(af[mi], bv[ni], acc[mi][ni], 0, 0, 0);
        __builtin_amdgcn_s_setprio(0);
      }
    }
    __syncthreads();  // drains stage t+1 (post-compute) + joins all waves
  }
#undef G1_STAGE

  // epilogue: frag ni even = a, odd = g (16-interleaved); act col block = bx*128
  const int orow = (lane >> 4) << 2;
  const int acb = bx * 128 + (wcol >> 1);
#pragma unroll
  for (int mi = 0; mi < 4; ++mi)
#pragma unroll
    for (int p = 0; p < 2; ++p) {
      const f32x4 va = acc[mi][2 * p];
      const f32x4 vg = acc[mi][2 * p + 1];
#pragma unroll
      for (int r = 0; r < 4; ++r) {
        const float g = vg[r];
        const float v = va[r] * (g / (1.0f + expf(-g)));
        const int gm = m0 + wrow + mi * 16 + orow + r;
        const int gc = acb + p * 16 + lr;
        act[(size_t)gm * FFN + gc] = f2bf(v);
      }
    }
}

// ---------------- K7: GEMM2  y = act @ w2[e] -------------------------------
// BM=128 x BN=128, BK=64, 8 waves (2M x 4N), wave out 64x32. Double-buffered.
__global__ __launch_bounds__(512, 4) void k_gemm2(
    const unsigned short* __restrict__ act, const unsigned short* __restrict__ w2t,
    const int* __restrict__ hdr, unsigned short* __restrict__ y) {
  const int total = hdr[25];
  const int m0 = blockIdx.y * 128;
  if (m0 >= total) return;
  int e = 0;
#pragma unroll
  for (int q = 1; q < 8; ++q) e += (m0 >= hdr[16 + q]) ? 1 : 0;
  const int n0 = blockIdx.x * 128;
  const unsigned short* w2e = w2t + (size_t)e * 1024 * 2048;

  __shared__ __align__(16) char Lds[2 * 32768]; // 64 KB: 2 x (A 16K + B 16K)

  const int tid  = threadIdx.x;
  const int lane = tid & 63;
  const int w    = tid >> 6;
  const int wrow = (w >> 2) * 64;
  const int wcol = (w & 3) * 32;
  const int lr   = lane & 15;
  const int qk16 = (lane >> 4) << 4;
  const int ldsw = w * 1024;

  const int srow = tid >> 3;
  const int cswz = (((tid & 7) ^ (srow & 7)) << 3);
  const int aoff0 = (m0 + srow) * FFN + cswz;
  const int boff0 = (n0 + srow) * FFN + cswz;

  f32x4 acc[4][2] = {};

#define G2_STAGE(base, kt) do {                                             \
    const unsigned short* as = act + (kt) * 64;                             \
    const unsigned short* ws = w2e + (kt) * 64;                             \
    GLDS16(as + aoff0,          Lds + (base) + ldsw);                       \
    GLDS16(as + aoff0 + 131072, Lds + (base) + 8192 + ldsw);                \
    GLDS16(ws + boff0,          Lds + (base) + 16384 + ldsw);               \
    GLDS16(ws + boff0 + 131072, Lds + (base) + 24576 + ldsw);               \
  } while (0)

  G2_STAGE(0, 0);
  __syncthreads();  // tile 0 resident

  for (int t = 0; t < 32; ++t) {
    if (t + 1 < 32) G2_STAGE(((t + 1) & 1) * 32768, t + 1); // prefetch next
    {
      const char* Ab = (const char*)Lds + (t & 1) * 32768;
      const char* Bb = Ab + 16384;
#pragma unroll
      for (int kk = 0; kk < 2; ++kk) {
        bf16x8 af[4], bv[2];
#pragma unroll
        for (int i = 0; i < 4; ++i) {
          const int ra = wrow + i * 16 + lr;
          af[i] = *reinterpret_cast<const bf16x8*>(Ab + ra * 128 + ((kk * 64 + qk16) ^ ((ra & 7) << 4)));
        }
#pragma unroll
        for (int i = 0; i < 2; ++i) {
          const int rb = wcol + i * 16 + lr;
          bv[i] = *reinterpret_cast<const bf16x8*>(Bb + rb * 128 + ((kk * 64 + qk16) ^ ((rb & 7) << 4)));
        }
        __builtin_amdgcn_s_setprio(1);
#pragma unroll
        for (int mi = 0; mi < 4; ++mi)
#pragma unroll
          for (int ni = 0; ni < 2; ++ni)
            acc[mi][ni] = __builtin_amdgcn_mfma_f32_16x16x32_bf16(af[mi], bv[ni], acc[mi][ni], 0, 0, 0);
        __builtin_amdgcn_s_setprio(0);
      }
    }
    __syncthreads();
  }
#undef G2_STAGE

  const int orow = (lane >> 4) << 2;
#pragma unroll
  for (int mi = 0; mi < 4; ++mi)
#pragma unroll
    for (int ni = 0; ni < 2; ++ni)
#pragma unroll
      for (int r = 0; r < 4; ++r) {
        const int gm = m0 + wrow + mi * 16 + orow + r;
        const int gc = n0 + wcol + ni * 16 + lr;
        y[(size_t)gm * HID + gc] = f2bf(acc[mi][ni][r]);
      }
}

// ---------------- K8: combine  out[t] = g0*y[r0] + g1*y[r1] ----------------
__global__ void k_combine(const unsigned short* __restrict__ y,
                          const int* __restrict__ rowmap,
                          const float* __restrict__ tok_gate,
                          float* __restrict__ out) {
  const int t = blockIdx.x;
  const int c = threadIdx.x << 2;
  const int r0 = rowmap[2 * t], r1 = rowmap[2 * t + 1];
  const float g0 = tok_gate[2 * t], g1 = tok_gate[2 * t + 1];
  const ushort4 a = *reinterpret_cast<const ushort4*>(y + (size_t)r0 * HID + c);
  const ushort4 b = *reinterpret_cast<const ushort4*>(y + (size_t)r1 * HID + c);
  float4 o;
  o.x = g0 * bf2f(a.x) + g1 * bf2f(b.x);
  o.y = g0 * bf2f(a.y) + g1 * bf2f(b.y);
  o.z = g0 * bf2f(a.z) + g1 * bf2f(b.z);
  o.w = g0 * bf2f(a.w) + g1 * bf2f(b.w);
  *reinterpret_cast<float4*>(out + (size_t)t * HID + c) = o;
}

extern "C" void kernel_launch(void* const* d_in, const int* in_sizes, int n_in,
                              void* d_out, int out_size, void* d_ws, size_t ws_size,
                              hipStream_t stream) {
  const float* x  = (const float*)d_in[0]; // [8192][1024]
  const float* wr = (const float*)d_in[1]; // [1024][8]
  const float* w1 = (const float*)d_in[2]; // [8][1024][4096]
  const float* w2 = (const float*)d_in[3]; // [8][2048][1024]
  float* out = (float*)d_out;              // [8192][1024] fp32

  // ws layout (~156 MB), region1 (xb+w1i) overlaid by (w2t+y) after gemm1.
  char* w = (char*)d_ws;
  int*   hdr        = (int*)w;
  int*   tok_idx    = (int*)(w + 1024);
  float* tok_gate   = (float*)(w + 1024 + 65536);
  int*   rowmap     = (int*)(w + 1024 + 2 * 65536);
  int*   bucket_tok = (int*)(w + 1024 + 3 * 65536);
  const size_t R1 = 524288;
  unsigned short* xb  = (unsigned short*)(w + R1);
  unsigned short* w1i = (unsigned short*)(w + R1 + 16777216);
  unsigned short* w2t = (unsigned short*)(w + R1);             // overlay
  unsigned short* yb  = (unsigned short*)(w + R1 + 33554432);  // overlay
  unsigned short* act = (unsigned short*)(w + R1 + 83886080);

  hipMemsetAsync(hdr, 0, 1024, stream);
  hipMemsetAsync(bucket_tok, 0, MAXPAD * sizeof(int), stream); // pad rows -> token 0

  k_router<<<T_TOK / 4, 256, 0, stream>>>(x, wr, tok_idx, tok_gate, hdr);
  k_offsets<<<1, 1, 0, stream>>>(hdr);
  k_scatter<<<(2 * T_TOK) / 256, 256, 0, stream>>>(tok_idx, hdr, bucket_tok, rowmap);
  k_cvt_x<<<(T_TOK * HID / 4) / 256, 256, 0, stream>>>(x, xb);
  k_cvtT<<<dim3(4096 / 64, 1024 / 64, 8), 256, 0, stream>>>(w1, w1i, 1024, 4096, 1);
  k_gemm1<<<dim3(16, MT1), 512, 0, stream>>>(xb, w1i, bucket_tok, hdr, act);
  k_cvtT<<<dim3(1024 / 64, 2048 / 64, 8), 256, 0, stream>>>(w2, w2t, 2048, 1024, 0);
  k_gemm2<<<dim3(8, MT1), 512, 0, stream>>>(act, w2t, hdr, yb);
  k_combine<<<T_TOK, 256, 0, stream>>>(yb, rowmap, tok_gate, out);
}

// Round 7
// 388.526 us; speedup vs baseline: 3.2384x; 1.5893x over previous
//
#include <hip/hip_runtime.h>
#include <hip/hip_bf16.h>
#include <math.h>

// MoE MLP: T=8192 tokens, 8 experts, top-2, HID=1024, FFN=2048 (GLU).
// R7: router stage rebuilt (LDS-staged wr^T, unrolled, zero global atomics;
// count/offsets in one tiny kernel; scatter uses block-reserve so only 512
// global atomics). GEMM/convert/combine kernels identical to verified R6.

#define T_TOK 8192
#define HID   1024
#define NEXP  8
#define FFN   2048
#define PADU  128
#define MAXPAD (2 * T_TOK + NEXP * PADU) /* 17408 */
#define MT1    (MAXPAD / 128)            /* 136 m-tiles */

typedef __attribute__((ext_vector_type(4))) float f32x4;
typedef __attribute__((ext_vector_type(8))) short bf16x8;
typedef __attribute__((ext_vector_type(8))) unsigned short u16x8;

static __device__ __forceinline__ unsigned short f2bf(float f) {
  unsigned int u = __float_as_uint(f);
  u += 0x7fffu + ((u >> 16) & 1u);
  return (unsigned short)(u >> 16);
}
static __device__ __forceinline__ float bf2f(unsigned short h) {
  return __uint_as_float(((unsigned int)h) << 16);
}

#define GLDS16(gsrc, ldst)                                                  \
  __builtin_amdgcn_global_load_lds(                                        \
      (const __attribute__((address_space(1))) void*)(gsrc),               \
      (__attribute__((address_space(3))) void*)(ldst), 16, 0, 0)

// ---------------- K1: router (fp64 acc, LDS wr^T, no atomics) --------------
// 8 waves/block, 1 token per wave; 1024 blocks.
__global__ __launch_bounds__(512) void k_router(
    const float* __restrict__ x, const float* __restrict__ wr,
    int* __restrict__ tok_idx, float* __restrict__ tok_gate) {
  __shared__ float wrT[8][1024];  // 32 KB, transposed: conflict-free reads
  const int tid = threadIdx.x;
#pragma unroll
  for (int p = 0; p < 4; ++p) {
    const int idx = tid + p * 512;  // float4 index, 0..2047
    const float4 v = reinterpret_cast<const float4*>(wr)[idx];
    const int f = idx * 4;          // flat elem; k = f>>3, e = f&7
    wrT[(f + 0) & 7][(f + 0) >> 3] = v.x;
    wrT[(f + 1) & 7][(f + 1) >> 3] = v.y;
    wrT[(f + 2) & 7][(f + 2) >> 3] = v.z;
    wrT[(f + 3) & 7][(f + 3) >> 3] = v.w;
  }
  __syncthreads();

  const int lane = tid & 63;
  const int wid  = tid >> 6;
  const int t    = blockIdx.x * 8 + wid;
  const float* xr = x + (size_t)t * HID;

  double acc[8] = {};
#pragma unroll
  for (int j = 0; j < 16; ++j) {
    const int k = lane + j * 64;
    const double xv = (double)xr[k];
#pragma unroll
    for (int e = 0; e < 8; ++e) acc[e] += xv * (double)wrT[e][k];
  }
#pragma unroll
  for (int e = 0; e < 8; ++e) {
#pragma unroll
    for (int off = 32; off > 0; off >>= 1) acc[e] += __shfl_down(acc[e], off);
  }
  if (lane == 0) {
    double v0 = -1e300, v1 = -1e300;
    int i0 = 0, i1 = 0;
#pragma unroll
    for (int e = 0; e < 8; ++e) {
      const double v = acc[e];
      if (v > v0)      { v1 = v0; i1 = i0; v0 = v; i0 = e; }
      else if (v > v1) { v1 = v; i1 = e; }
    }
    const float g0 = 1.0f / (1.0f + expf((float)(v1 - v0)));
    tok_idx[2 * t]     = i0;
    tok_idx[2 * t + 1] = i1;
    tok_gate[2 * t]     = g0;
    tok_gate[2 * t + 1] = 1.0f - g0;
  }
}

// ---------------- K2: count + padded offsets (single block) ----------------
// hdr: [0..7]=counts, [8..15]=cursor(=0), [16..23]=off_pad, [24],[25]=total
__global__ void k_count(const int* __restrict__ tok_idx, int* __restrict__ hdr) {
  __shared__ int h[8];
  const int tid = threadIdx.x;
  if (tid < 8) h[tid] = 0;
  __syncthreads();
  int c[8] = {0, 0, 0, 0, 0, 0, 0, 0};
  for (int i = tid; i < 2 * T_TOK; i += 256) {
    const int e = tok_idx[i];
#pragma unroll
    for (int q = 0; q < 8; ++q) c[q] += (e == q) ? 1 : 0;
  }
#pragma unroll
  for (int q = 0; q < 8; ++q) {
#pragma unroll
    for (int off = 32; off > 0; off >>= 1) c[q] += __shfl_down(c[q], off);
  }
  if ((tid & 63) == 0) {
#pragma unroll
    for (int q = 0; q < 8; ++q) atomicAdd(&h[q], c[q]);
  }
  __syncthreads();
  if (tid == 0) {
    int off = 0;
#pragma unroll
    for (int e = 0; e < 8; ++e) {
      hdr[e] = h[e];
      hdr[8 + e] = 0;
      hdr[16 + e] = off;
      off += (h[e] + PADU - 1) & ~(PADU - 1);
    }
    hdr[24] = off;
    hdr[25] = off;
  }
}

// ---------------- K3: scatter (block-reserve: 8 global atomics/block) ------
__global__ void k_scatter(const int* __restrict__ tok_idx, int* __restrict__ hdr,
                          int* __restrict__ bucket_tok, int* __restrict__ rowmap) {
  __shared__ int lcnt[8], lbase[8];
  const int tid = threadIdx.x;
  const int i = blockIdx.x * 256 + tid;
  const int e = tok_idx[i];
  if (tid < 8) lcnt[tid] = 0;
  __syncthreads();
  const int pos = atomicAdd(&lcnt[e], 1);       // LDS atomic: rank in block
  __syncthreads();
  if (tid < 8) lbase[tid] = atomicAdd(&hdr[8 + tid], lcnt[tid]); // reserve
  __syncthreads();
  const int r = hdr[16 + e] + lbase[e] + pos;
  bucket_tok[r] = i >> 1;
  rowmap[i] = r;
}

// ---------------- K4: x fp32 -> bf16 ---------------------------------------
__global__ void k_cvt_x(const float* __restrict__ x, unsigned short* __restrict__ xb) {
  const int i = blockIdx.x * 256 + threadIdx.x;
  const float4 v = reinterpret_cast<const float4*>(x)[i];
  ushort4 h;
  h.x = f2bf(v.x); h.y = f2bf(v.y); h.z = f2bf(v.z); h.w = f2bf(v.w);
  reinterpret_cast<ushort4*>(xb)[i] = h;
}

// ---------------- K5: convert+transpose src[e][R][C] f32 -> dst[e][map(c)][R]
// ilv=1: c -> interleave16(a,g) row for fused-swiglu gemm1 B operand.
__global__ void k_cvtT(const float* __restrict__ src, unsigned short* __restrict__ dst,
                       int R, int C, int ilv) {
  const int e  = blockIdx.z;
  const int c0 = blockIdx.x * 64;
  const int r0 = blockIdx.y * 64;
  __shared__ unsigned short t[64][72];
  const int tid = threadIdx.x;
  const float* s = src + (size_t)e * R * C;
  unsigned short* d = dst + (size_t)e * R * C;
#pragma unroll
  for (int p = 0; p < 4; ++p) {
    const int idx = tid + p * 256;
    const int r  = idx >> 4;
    const int c4 = (idx & 15) << 2;
    const float4 v = *reinterpret_cast<const float4*>(s + (size_t)(r0 + r) * C + c0 + c4);
    t[c4 + 0][r] = f2bf(v.x); t[c4 + 1][r] = f2bf(v.y);
    t[c4 + 2][r] = f2bf(v.z); t[c4 + 3][r] = f2bf(v.w);
  }
  __syncthreads();
#pragma unroll
  for (int p = 0; p < 2; ++p) {
    const int idx = tid + p * 256;  // 0..511
    const int c  = idx >> 3;
    const int r8 = (idx & 7) << 3;
    u16x8 v;
#pragma unroll
    for (int i = 0; i < 8; ++i) v[i] = t[c][r8 + i];
    const int n = c0 + c;
    int row = n;
    if (ilv) {
      const int j = n & (FFN - 1);
      const int half = n >> 11;
      row = ((j >> 4) << 5) + (half << 4) + (j & 15);
    }
    *reinterpret_cast<u16x8*>(d + (size_t)row * R + r0 + r8) = v;
  }
}

// ---------------- K6: GEMM1  act = (x@w1a) * silu(x@w1g) -------------------
// BM=128 x BN=256(interleaved a/g), BK=64, 8 waves (2M x 4N), wave out 64x64.
// Double-buffered LDS; STAGE(t+1) before compute(t); __syncthreads per step.
__global__ __launch_bounds__(512, 2) void k_gemm1(
    const unsigned short* __restrict__ xb, const unsigned short* __restrict__ w1i,
    const int* __restrict__ bucket_tok, const int* __restrict__ hdr,
    unsigned short* __restrict__ act) {
  const int total = hdr[25];
  const int m0 = blockIdx.y * 128;
  if (m0 >= total) return;
  int e = 0;
#pragma unroll
  for (int q = 1; q < 8; ++q) e += (m0 >= hdr[16 + q]) ? 1 : 0;
  const int bx = blockIdx.x;  // 16 tiles of 256 interleaved cols
  const unsigned short* w1e = w1i + (size_t)e * 4096 * 1024;

  __shared__ __align__(16) char Lds[2 * 49152]; // 96 KB: 2 x (A 16K + B 32K)

  const int tid  = threadIdx.x;
  const int lane = tid & 63;
  const int w    = tid >> 6;
  const int wrow = (w >> 2) * 64;
  const int wcol = (w & 3) * 64;
  const int lr   = lane & 15;
  const int qk16 = (lane >> 4) << 4;
  const int ldsw = w * 1024;  // wave-uniform base within each 8KB stage round

  const int srow = tid >> 3;                         // 0..63
  const int cswz = (((tid & 7) ^ (srow & 7)) << 3);  // pre-swizzled k offset
  const int aoffA0 = bucket_tok[m0 + srow] * 1024 + cswz;
  const int aoffA1 = bucket_tok[m0 + 64 + srow] * 1024 + cswz;
  const int boffB0 = (bx * 256 + srow) * 1024 + cswz;

  f32x4 acc[4][4] = {};

#define G1_STAGE(base, kt) do {                                             \
    const unsigned short* xs = xb + (kt) * 64;                              \
    const unsigned short* ws = w1e + (kt) * 64;                             \
    GLDS16(xs + aoffA0,           Lds + (base) + ldsw);                     \
    GLDS16(xs + aoffA1,           Lds + (base) + 8192 + ldsw);              \
    GLDS16(ws + boffB0,           Lds + (base) + 16384 + ldsw);             \
    GLDS16(ws + boffB0 + 65536,   Lds + (base) + 24576 + ldsw);             \
    GLDS16(ws + boffB0 + 131072,  Lds + (base) + 32768 + ldsw);             \
    GLDS16(ws + boffB0 + 196608,  Lds + (base) + 40960 + ldsw);             \
  } while (0)

  G1_STAGE(0, 0);
  __syncthreads();  // tile 0 resident

  for (int t = 0; t < 16; ++t) {
    if (t + 1 < 16) G1_STAGE(((t + 1) & 1) * 49152, t + 1); // prefetch next
    {
      const char* Ab = (const char*)Lds + (t & 1) * 49152;
      const char* Bb = Ab + 16384;
#pragma unroll
      for (int kk = 0; kk < 2; ++kk) {
        bf16x8 af[4], bv[4];
#pragma unroll
        for (int i = 0; i < 4; ++i) {
          const int ra = wrow + i * 16 + lr;
          af[i] = *reinterpret_cast<const bf16x8*>(Ab + ra * 128 + ((kk * 64 + qk16) ^ ((ra & 7) << 4)));
          const int rb = wcol + i * 16 + lr;
          bv[i] = *reinterpret_cast<const bf16x8*>(Bb + rb * 128 + ((kk * 64 + qk16) ^ ((rb & 7) << 4)));
        }
        __builtin_amdgcn_s_setprio(1);
#pragma unroll
        for (int mi = 0; mi < 4; ++mi)
#pragma unroll
          for (int ni = 0; ni < 4; ++ni)
            acc[mi][ni] = __builtin_amdgcn_mfma_f32_16x16x32_bf16(af[mi], bv[ni], acc[mi][ni], 0, 0, 0);
        __builtin_amdgcn_s_setprio(0);
      }
    }
    __syncthreads();  // drains stage t+1 (post-compute) + joins all waves
  }
#undef G1_STAGE

  // epilogue: frag ni even = a, odd = g (16-interleaved); act col block = bx*128
  const int orow = (lane >> 4) << 2;
  const int acb = bx * 128 + (wcol >> 1);
#pragma unroll
  for (int mi = 0; mi < 4; ++mi)
#pragma unroll
    for (int p = 0; p < 2; ++p) {
      const f32x4 va = acc[mi][2 * p];
      const f32x4 vg = acc[mi][2 * p + 1];
#pragma unroll
      for (int r = 0; r < 4; ++r) {
        const float g = vg[r];
        const float v = va[r] * (g / (1.0f + expf(-g)));
        const int gm = m0 + wrow + mi * 16 + orow + r;
        const int gc = acb + p * 16 + lr;
        act[(size_t)gm * FFN + gc] = f2bf(v);
      }
    }
}

// ---------------- K7: GEMM2  y = act @ w2[e] -------------------------------
// BM=128 x BN=128, BK=64, 8 waves (2M x 4N), wave out 64x32. Double-buffered.
__global__ __launch_bounds__(512, 4) void k_gemm2(
    const unsigned short* __restrict__ act, const unsigned short* __restrict__ w2t,
    const int* __restrict__ hdr, unsigned short* __restrict__ y) {
  const int total = hdr[25];
  const int m0 = blockIdx.y * 128;
  if (m0 >= total) return;
  int e = 0;
#pragma unroll
  for (int q = 1; q < 8; ++q) e += (m0 >= hdr[16 + q]) ? 1 : 0;
  const int n0 = blockIdx.x * 128;
  const unsigned short* w2e = w2t + (size_t)e * 1024 * 2048;

  __shared__ __align__(16) char Lds[2 * 32768]; // 64 KB: 2 x (A 16K + B 16K)

  const int tid  = threadIdx.x;
  const int lane = tid & 63;
  const int w    = tid >> 6;
  const int wrow = (w >> 2) * 64;
  const int wcol = (w & 3) * 32;
  const int lr   = lane & 15;
  const int qk16 = (lane >> 4) << 4;
  const int ldsw = w * 1024;

  const int srow = tid >> 3;
  const int cswz = (((tid & 7) ^ (srow & 7)) << 3);
  const int aoff0 = (m0 + srow) * FFN + cswz;
  const int boff0 = (n0 + srow) * FFN + cswz;

  f32x4 acc[4][2] = {};

#define G2_STAGE(base, kt) do {                                             \
    const unsigned short* as = act + (kt) * 64;                             \
    const unsigned short* ws = w2e + (kt) * 64;                             \
    GLDS16(as + aoff0,          Lds + (base) + ldsw);                       \
    GLDS16(as + aoff0 + 131072, Lds + (base) + 8192 + ldsw);                \
    GLDS16(ws + boff0,          Lds + (base) + 16384 + ldsw);               \
    GLDS16(ws + boff0 + 131072, Lds + (base) + 24576 + ldsw);               \
  } while (0)

  G2_STAGE(0, 0);
  __syncthreads();  // tile 0 resident

  for (int t = 0; t < 32; ++t) {
    if (t + 1 < 32) G2_STAGE(((t + 1) & 1) * 32768, t + 1); // prefetch next
    {
      const char* Ab = (const char*)Lds + (t & 1) * 32768;
      const char* Bb = Ab + 16384;
#pragma unroll
      for (int kk = 0; kk < 2; ++kk) {
        bf16x8 af[4], bv[2];
#pragma unroll
        for (int i = 0; i < 4; ++i) {
          const int ra = wrow + i * 16 + lr;
          af[i] = *reinterpret_cast<const bf16x8*>(Ab + ra * 128 + ((kk * 64 + qk16) ^ ((ra & 7) << 4)));
        }
#pragma unroll
        for (int i = 0; i < 2; ++i) {
          const int rb = wcol + i * 16 + lr;
          bv[i] = *reinterpret_cast<const bf16x8*>(Bb + rb * 128 + ((kk * 64 + qk16) ^ ((rb & 7) << 4)));
        }
        __builtin_amdgcn_s_setprio(1);
#pragma unroll
        for (int mi = 0; mi < 4; ++mi)
#pragma unroll
          for (int ni = 0; ni < 2; ++ni)
            acc[mi][ni] = __builtin_amdgcn_mfma_f32_16x16x32_bf16(af[mi], bv[ni], acc[mi][ni], 0, 0, 0);
        __builtin_amdgcn_s_setprio(0);
      }
    }
    __syncthreads();
  }
#undef G2_STAGE

  const int orow = (lane >> 4) << 2;
#pragma unroll
  for (int mi = 0; mi < 4; ++mi)
#pragma unroll
    for (int ni = 0; ni < 2; ++ni)
#pragma unroll
      for (int r = 0; r < 4; ++r) {
        const int gm = m0 + wrow + mi * 16 + orow + r;
        const int gc = n0 + wcol + ni * 16 + lr;
        y[(size_t)gm * HID + gc] = f2bf(acc[mi][ni][r]);
      }
}

// ---------------- K8: combine  out[t] = g0*y[r0] + g1*y[r1] ----------------
__global__ void k_combine(const unsigned short* __restrict__ y,
                          const int* __restrict__ rowmap,
                          const float* __restrict__ tok_gate,
                          float* __restrict__ out) {
  const int t = blockIdx.x;
  const int c = threadIdx.x << 2;
  const int r0 = rowmap[2 * t], r1 = rowmap[2 * t + 1];
  const float g0 = tok_gate[2 * t], g1 = tok_gate[2 * t + 1];
  const ushort4 a = *reinterpret_cast<const ushort4*>(y + (size_t)r0 * HID + c);
  const ushort4 b = *reinterpret_cast<const ushort4*>(y + (size_t)r1 * HID + c);
  float4 o;
  o.x = g0 * bf2f(a.x) + g1 * bf2f(b.x);
  o.y = g0 * bf2f(a.y) + g1 * bf2f(b.y);
  o.z = g0 * bf2f(a.z) + g1 * bf2f(b.z);
  o.w = g0 * bf2f(a.w) + g1 * bf2f(b.w);
  *reinterpret_cast<float4*>(out + (size_t)t * HID + c) = o;
}

extern "C" void kernel_launch(void* const* d_in, const int* in_sizes, int n_in,
                              void* d_out, int out_size, void* d_ws, size_t ws_size,
                              hipStream_t stream) {
  const float* x  = (const float*)d_in[0]; // [8192][1024]
  const float* wr = (const float*)d_in[1]; // [1024][8]
  const float* w1 = (const float*)d_in[2]; // [8][1024][4096]
  const float* w2 = (const float*)d_in[3]; // [8][2048][1024]
  float* out = (float*)d_out;              // [8192][1024] fp32

  // ws layout (~156 MB), region1 (xb+w1i) overlaid by (w2t+y) after gemm1.
  char* w = (char*)d_ws;
  int*   hdr        = (int*)w;
  int*   tok_idx    = (int*)(w + 1024);
  float* tok_gate   = (float*)(w + 1024 + 65536);
  int*   rowmap     = (int*)(w + 1024 + 2 * 65536);
  int*   bucket_tok = (int*)(w + 1024 + 3 * 65536);
  const size_t R1 = 524288;
  unsigned short* xb  = (unsigned short*)(w + R1);
  unsigned short* w1i = (unsigned short*)(w + R1 + 16777216);
  unsigned short* w2t = (unsigned short*)(w + R1);             // overlay
  unsigned short* yb  = (unsigned short*)(w + R1 + 33554432);  // overlay
  unsigned short* act = (unsigned short*)(w + R1 + 83886080);

  hipMemsetAsync(bucket_tok, 0, MAXPAD * sizeof(int), stream); // pad rows -> token 0

  k_router<<<T_TOK / 8, 512, 0, stream>>>(x, wr, tok_idx, tok_gate);
  k_count<<<1, 256, 0, stream>>>(tok_idx, hdr);
  k_scatter<<<(2 * T_TOK) / 256, 256, 0, stream>>>(tok_idx, hdr, bucket_tok, rowmap);
  k_cvt_x<<<(T_TOK * HID / 4) / 256, 256, 0, stream>>>(x, xb);
  k_cvtT<<<dim3(4096 / 64, 1024 / 64, 8), 256, 0, stream>>>(w1, w1i, 1024, 4096, 1);
  k_gemm1<<<dim3(16, MT1), 512, 0, stream>>>(xb, w1i, bucket_tok, hdr, act);
  k_cvtT<<<dim3(1024 / 64, 2048 / 64, 8), 256, 0, stream>>>(w2, w2t, 2048, 1024, 0);
  k_gemm2<<<dim3(8, MT1), 512, 0, stream>>>(act, w2t, hdr, yb);
  k_combine<<<T_TOK, 256, 0, stream>>>(yb, rowmap, tok_gate, out);
}

// Round 8
// 388.224 us; speedup vs baseline: 3.2410x; 1.0008x over previous
//
#include <hip/hip_runtime.h>
#include <hip/hip_bf16.h>
#include <math.h>

// MoE MLP: T=8192 tokens, 8 experts, top-2, HID=1024, FFN=2048 (GLU).
// R8: depth-3 counted-vmcnt pipeline retry with sched_barrier(0) ordering
// fences (rule #18) and fused "s_waitcnt vmcnt(N); s_barrier" asm blocks.
// All non-GEMM kernels identical to verified R7.

#define T_TOK 8192
#define HID   1024
#define NEXP  8
#define FFN   2048
#define PADU  128
#define MAXPAD (2 * T_TOK + NEXP * PADU) /* 17408 */
#define MT1    (MAXPAD / 128)            /* 136 m-tiles */

typedef __attribute__((ext_vector_type(4))) float f32x4;
typedef __attribute__((ext_vector_type(8))) short bf16x8;
typedef __attribute__((ext_vector_type(8))) unsigned short u16x8;

static __device__ __forceinline__ unsigned short f2bf(float f) {
  unsigned int u = __float_as_uint(f);
  u += 0x7fffu + ((u >> 16) & 1u);
  return (unsigned short)(u >> 16);
}
static __device__ __forceinline__ float bf2f(unsigned short h) {
  return __uint_as_float(((unsigned int)h) << 16);
}

#define GLDS16(gsrc, ldst)                                                  \
  __builtin_amdgcn_global_load_lds(                                        \
      (const __attribute__((address_space(1))) void*)(gsrc),               \
      (__attribute__((address_space(3))) void*)(ldst), 16, 0, 0)

#define SCHED_FENCE() __builtin_amdgcn_sched_barrier(0)
// fused counted-wait + barrier: single asm stmt so nothing lands between
#define WAIT_BAR(n) asm volatile("s_waitcnt vmcnt(" #n ")\n\ts_barrier" ::: "memory")

// ---------------- K1: router (fp64 acc, LDS wr^T, no atomics) --------------
__global__ __launch_bounds__(512) void k_router(
    const float* __restrict__ x, const float* __restrict__ wr,
    int* __restrict__ tok_idx, float* __restrict__ tok_gate) {
  __shared__ float wrT[8][1024];
  const int tid = threadIdx.x;
#pragma unroll
  for (int p = 0; p < 4; ++p) {
    const int idx = tid + p * 512;
    const float4 v = reinterpret_cast<const float4*>(wr)[idx];
    const int f = idx * 4;
    wrT[(f + 0) & 7][(f + 0) >> 3] = v.x;
    wrT[(f + 1) & 7][(f + 1) >> 3] = v.y;
    wrT[(f + 2) & 7][(f + 2) >> 3] = v.z;
    wrT[(f + 3) & 7][(f + 3) >> 3] = v.w;
  }
  __syncthreads();

  const int lane = tid & 63;
  const int wid  = tid >> 6;
  const int t    = blockIdx.x * 8 + wid;
  const float* xr = x + (size_t)t * HID;

  double acc[8] = {};
#pragma unroll
  for (int j = 0; j < 16; ++j) {
    const int k = lane + j * 64;
    const double xv = (double)xr[k];
#pragma unroll
    for (int e = 0; e < 8; ++e) acc[e] += xv * (double)wrT[e][k];
  }
#pragma unroll
  for (int e = 0; e < 8; ++e) {
#pragma unroll
    for (int off = 32; off > 0; off >>= 1) acc[e] += __shfl_down(acc[e], off);
  }
  if (lane == 0) {
    double v0 = -1e300, v1 = -1e300;
    int i0 = 0, i1 = 0;
#pragma unroll
    for (int e = 0; e < 8; ++e) {
      const double v = acc[e];
      if (v > v0)      { v1 = v0; i1 = i0; v0 = v; i0 = e; }
      else if (v > v1) { v1 = v; i1 = e; }
    }
    const float g0 = 1.0f / (1.0f + expf((float)(v1 - v0)));
    tok_idx[2 * t]     = i0;
    tok_idx[2 * t + 1] = i1;
    tok_gate[2 * t]     = g0;
    tok_gate[2 * t + 1] = 1.0f - g0;
  }
}

// ---------------- K2: count + padded offsets (single block) ----------------
__global__ void k_count(const int* __restrict__ tok_idx, int* __restrict__ hdr) {
  __shared__ int h[8];
  const int tid = threadIdx.x;
  if (tid < 8) h[tid] = 0;
  __syncthreads();
  int c[8] = {0, 0, 0, 0, 0, 0, 0, 0};
  for (int i = tid; i < 2 * T_TOK; i += 256) {
    const int e = tok_idx[i];
#pragma unroll
    for (int q = 0; q < 8; ++q) c[q] += (e == q) ? 1 : 0;
  }
#pragma unroll
  for (int q = 0; q < 8; ++q) {
#pragma unroll
    for (int off = 32; off > 0; off >>= 1) c[q] += __shfl_down(c[q], off);
  }
  if ((tid & 63) == 0) {
#pragma unroll
    for (int q = 0; q < 8; ++q) atomicAdd(&h[q], c[q]);
  }
  __syncthreads();
  if (tid == 0) {
    int off = 0;
#pragma unroll
    for (int e = 0; e < 8; ++e) {
      hdr[e] = h[e];
      hdr[8 + e] = 0;
      hdr[16 + e] = off;
      off += (h[e] + PADU - 1) & ~(PADU - 1);
    }
    hdr[24] = off;
    hdr[25] = off;
  }
}

// ---------------- K3: scatter (block-reserve: 8 global atomics/block) ------
__global__ void k_scatter(const int* __restrict__ tok_idx, int* __restrict__ hdr,
                          int* __restrict__ bucket_tok, int* __restrict__ rowmap) {
  __shared__ int lcnt[8], lbase[8];
  const int tid = threadIdx.x;
  const int i = blockIdx.x * 256 + tid;
  const int e = tok_idx[i];
  if (tid < 8) lcnt[tid] = 0;
  __syncthreads();
  const int pos = atomicAdd(&lcnt[e], 1);
  __syncthreads();
  if (tid < 8) lbase[tid] = atomicAdd(&hdr[8 + tid], lcnt[tid]);
  __syncthreads();
  const int r = hdr[16 + e] + lbase[e] + pos;
  bucket_tok[r] = i >> 1;
  rowmap[i] = r;
}

// ---------------- K4: x fp32 -> bf16 ---------------------------------------
__global__ void k_cvt_x(const float* __restrict__ x, unsigned short* __restrict__ xb) {
  const int i = blockIdx.x * 256 + threadIdx.x;
  const float4 v = reinterpret_cast<const float4*>(x)[i];
  ushort4 h;
  h.x = f2bf(v.x); h.y = f2bf(v.y); h.z = f2bf(v.z); h.w = f2bf(v.w);
  reinterpret_cast<ushort4*>(xb)[i] = h;
}

// ---------------- K5: convert+transpose src[e][R][C] f32 -> dst[e][map(c)][R]
__global__ void k_cvtT(const float* __restrict__ src, unsigned short* __restrict__ dst,
                       int R, int C, int ilv) {
  const int e  = blockIdx.z;
  const int c0 = blockIdx.x * 64;
  const int r0 = blockIdx.y * 64;
  __shared__ unsigned short t[64][72];
  const int tid = threadIdx.x;
  const float* s = src + (size_t)e * R * C;
  unsigned short* d = dst + (size_t)e * R * C;
#pragma unroll
  for (int p = 0; p < 4; ++p) {
    const int idx = tid + p * 256;
    const int r  = idx >> 4;
    const int c4 = (idx & 15) << 2;
    const float4 v = *reinterpret_cast<const float4*>(s + (size_t)(r0 + r) * C + c0 + c4);
    t[c4 + 0][r] = f2bf(v.x); t[c4 + 1][r] = f2bf(v.y);
    t[c4 + 2][r] = f2bf(v.z); t[c4 + 3][r] = f2bf(v.w);
  }
  __syncthreads();
#pragma unroll
  for (int p = 0; p < 2; ++p) {
    const int idx = tid + p * 256;
    const int c  = idx >> 3;
    const int r8 = (idx & 7) << 3;
    u16x8 v;
#pragma unroll
    for (int i = 0; i < 8; ++i) v[i] = t[c][r8 + i];
    const int n = c0 + c;
    int row = n;
    if (ilv) {
      const int j = n & (FFN - 1);
      const int half = n >> 11;
      row = ((j >> 4) << 5) + (half << 4) + (j & 15);
    }
    *reinterpret_cast<u16x8*>(d + (size_t)row * R + r0 + r8) = v;
  }
}

// ---------------- K6: GEMM1  act = (x@w1a) * silu(x@w1g) -------------------
// BM=128 x BN=256(interleaved a/g), BK=64, 8 waves, wave out 64x64.
// Depth-3 pipeline: counted vmcnt(6), fused wait+barrier, sched fences.
__global__ __launch_bounds__(512, 2) void k_gemm1(
    const unsigned short* __restrict__ xb, const unsigned short* __restrict__ w1i,
    const int* __restrict__ bucket_tok, const int* __restrict__ hdr,
    unsigned short* __restrict__ act) {
  const int total = hdr[25];
  const int m0 = blockIdx.y * 128;
  if (m0 >= total) return;
  int e = 0;
#pragma unroll
  for (int q = 1; q < 8; ++q) e += (m0 >= hdr[16 + q]) ? 1 : 0;
  const int bx = blockIdx.x;
  const unsigned short* w1e = w1i + (size_t)e * 4096 * 1024;

  __shared__ __align__(16) char Lds[3 * 49152]; // 144 KB: 3 x (A 16K + B 32K)

  const int tid  = threadIdx.x;
  const int lane = tid & 63;
  const int w    = tid >> 6;
  const int wrow = (w >> 2) * 64;
  const int wcol = (w & 3) * 64;
  const int lr   = lane & 15;
  const int qk16 = (lane >> 4) << 4;
  const int ldsw = w * 1024;

  const int srow = tid >> 3;
  const int cswz = (((tid & 7) ^ (srow & 7)) << 3);
  const int aoffA0 = bucket_tok[m0 + srow] * 1024 + cswz;
  const int aoffA1 = bucket_tok[m0 + 64 + srow] * 1024 + cswz;
  const int boffB0 = (bx * 256 + srow) * 1024 + cswz;

  f32x4 acc[4][4] = {};

#define G1_STAGE(base, kt) do {                                             \
    const unsigned short* xs = xb + (kt) * 64;                              \
    const unsigned short* ws = w1e + (kt) * 64;                             \
    GLDS16(xs + aoffA0,           Lds + (base) + ldsw);                     \
    GLDS16(xs + aoffA1,           Lds + (base) + 8192 + ldsw);              \
    GLDS16(ws + boffB0,           Lds + (base) + 16384 + ldsw);             \
    GLDS16(ws + boffB0 + 65536,   Lds + (base) + 24576 + ldsw);             \
    GLDS16(ws + boffB0 + 131072,  Lds + (base) + 32768 + ldsw);             \
    GLDS16(ws + boffB0 + 196608,  Lds + (base) + 40960 + ldsw);             \
  } while (0)

  G1_STAGE(0, 0);
  G1_STAGE(49152, 1);
  SCHED_FENCE();
  WAIT_BAR(6);          // stage 0 landed (all waves)
  SCHED_FENCE();

  int cur = 0, nxt2 = 2; // buffer of stage t, buffer of stage t+2
  for (int t = 0; t < 16; ++t) {
    if (t + 2 < 16) {
      G1_STAGE(nxt2 * 49152, t + 2);
      SCHED_FENCE();    // pin: stage issue BEFORE compute & wait
    }
    {
      const char* Ab = (const char*)Lds + cur * 49152;
      const char* Bb = Ab + 16384;
#pragma unroll
      for (int kk = 0; kk < 2; ++kk) {
        bf16x8 af[4], bv[4];
#pragma unroll
        for (int i = 0; i < 4; ++i) {
          const int ra = wrow + i * 16 + lr;
          af[i] = *reinterpret_cast<const bf16x8*>(Ab + ra * 128 + ((kk * 64 + qk16) ^ ((ra & 7) << 4)));
          const int rb = wcol + i * 16 + lr;
          bv[i] = *reinterpret_cast<const bf16x8*>(Bb + rb * 128 + ((kk * 64 + qk16) ^ ((rb & 7) << 4)));
        }
        __builtin_amdgcn_s_setprio(1);
#pragma unroll
        for (int mi = 0; mi < 4; ++mi)
#pragma unroll
          for (int ni = 0; ni < 4; ++ni)
            acc[mi][ni] = __builtin_amdgcn_mfma_f32_16x16x32_bf16(af[mi], bv[ni], acc[mi][ni], 0, 0, 0);
        __builtin_amdgcn_s_setprio(0);
      }
    }
    SCHED_FENCE();      // pin: compute (incl. ds_reads) BEFORE the wait
    if (t + 2 < 16)      WAIT_BAR(6);  // stage t+1 landed; t+2 stays in flight
    else if (t + 1 < 16) WAIT_BAR(0);  // penultimate: drain last stage
    SCHED_FENCE();
    cur = (cur == 2) ? 0 : (cur + 1);
    nxt2 = (nxt2 == 2) ? 0 : (nxt2 + 1);
  }
#undef G1_STAGE

  // epilogue: frag ni even = a, odd = g (16-interleaved)
  const int orow = (lane >> 4) << 2;
  const int acb = bx * 128 + (wcol >> 1);
#pragma unroll
  for (int mi = 0; mi < 4; ++mi)
#pragma unroll
    for (int p = 0; p < 2; ++p) {
      const f32x4 va = acc[mi][2 * p];
      const f32x4 vg = acc[mi][2 * p + 1];
#pragma unroll
      for (int r = 0; r < 4; ++r) {
        const float g = vg[r];
        const float v = va[r] * (g / (1.0f + expf(-g)));
        const int gm = m0 + wrow + mi * 16 + orow + r;
        const int gc = acb + p * 16 + lr;
        act[(size_t)gm * FFN + gc] = f2bf(v);
      }
    }
}

// ---------------- K7: GEMM2  y = act @ w2[e] -------------------------------
// BM=128 x BN=128, BK=64, 8 waves, wave out 64x32. Depth-3, vmcnt(4).
__global__ __launch_bounds__(512, 2) void k_gemm2(
    const unsigned short* __restrict__ act, const unsigned short* __restrict__ w2t,
    const int* __restrict__ hdr, unsigned short* __restrict__ y) {
  const int total = hdr[25];
  const int m0 = blockIdx.y * 128;
  if (m0 >= total) return;
  int e = 0;
#pragma unroll
  for (int q = 1; q < 8; ++q) e += (m0 >= hdr[16 + q]) ? 1 : 0;
  const int n0 = blockIdx.x * 128;
  const unsigned short* w2e = w2t + (size_t)e * 1024 * 2048;

  __shared__ __align__(16) char Lds[3 * 32768]; // 96 KB: 3 x (A 16K + B 16K)

  const int tid  = threadIdx.x;
  const int lane = tid & 63;
  const int w    = tid >> 6;
  const int wrow = (w >> 2) * 64;
  const int wcol = (w & 3) * 32;
  const int lr   = lane & 15;
  const int qk16 = (lane >> 4) << 4;
  const int ldsw = w * 1024;

  const int srow = tid >> 3;
  const int cswz = (((tid & 7) ^ (srow & 7)) << 3);
  const int aoff0 = (m0 + srow) * FFN + cswz;
  const int boff0 = (n0 + srow) * FFN + cswz;

  f32x4 acc[4][2] = {};

#define G2_STAGE(base, kt) do {                                             \
    const unsigned short* as = act + (kt) * 64;                             \
    const unsigned short* ws = w2e + (kt) * 64;                             \
    GLDS16(as + aoff0,          Lds + (base) + ldsw);                       \
    GLDS16(as + aoff0 + 131072, Lds + (base) + 8192 + ldsw);                \
    GLDS16(ws + boff0,          Lds + (base) + 16384 + ldsw);               \
    GLDS16(ws + boff0 + 131072, Lds + (base) + 24576 + ldsw);               \
  } while (0)

  G2_STAGE(0, 0);
  G2_STAGE(32768, 1);
  SCHED_FENCE();
  WAIT_BAR(4);
  SCHED_FENCE();

  int cur = 0, nxt2 = 2;
  for (int t = 0; t < 32; ++t) {
    if (t + 2 < 32) {
      G2_STAGE(nxt2 * 32768, t + 2);
      SCHED_FENCE();
    }
    {
      const char* Ab = (const char*)Lds + cur * 32768;
      const char* Bb = Ab + 16384;
#pragma unroll
      for (int kk = 0; kk < 2; ++kk) {
        bf16x8 af[4], bv[2];
#pragma unroll
        for (int i = 0; i < 4; ++i) {
          const int ra = wrow + i * 16 + lr;
          af[i] = *reinterpret_cast<const bf16x8*>(Ab + ra * 128 + ((kk * 64 + qk16) ^ ((ra & 7) << 4)));
        }
#pragma unroll
        for (int i = 0; i < 2; ++i) {
          const int rb = wcol + i * 16 + lr;
          bv[i] = *reinterpret_cast<const bf16x8*>(Bb + rb * 128 + ((kk * 64 + qk16) ^ ((rb & 7) << 4)));
        }
        __builtin_amdgcn_s_setprio(1);
#pragma unroll
        for (int mi = 0; mi < 4; ++mi)
#pragma unroll
          for (int ni = 0; ni < 2; ++ni)
            acc[mi][ni] = __builtin_amdgcn_mfma_f32_16x16x32_bf16(af[mi], bv[ni], acc[mi][ni], 0, 0, 0);
        __builtin_amdgcn_s_setprio(0);
      }
    }
    SCHED_FENCE();
    if (t + 2 < 32)      WAIT_BAR(4);
    else if (t + 1 < 32) WAIT_BAR(0);
    SCHED_FENCE();
    cur = (cur == 2) ? 0 : (cur + 1);
    nxt2 = (nxt2 == 2) ? 0 : (nxt2 + 1);
  }
#undef G2_STAGE

  const int orow = (lane >> 4) << 2;
#pragma unroll
  for (int mi = 0; mi < 4; ++mi)
#pragma unroll
    for (int ni = 0; ni < 2; ++ni)
#pragma unroll
      for (int r = 0; r < 4; ++r) {
        const int gm = m0 + wrow + mi * 16 + orow + r;
        const int gc = n0 + wcol + ni * 16 + lr;
        y[(size_t)gm * HID + gc] = f2bf(acc[mi][ni][r]);
      }
}

// ---------------- K8: combine  out[t] = g0*y[r0] + g1*y[r1] ----------------
__global__ void k_combine(const unsigned short* __restrict__ y,
                          const int* __restrict__ rowmap,
                          const float* __restrict__ tok_gate,
                          float* __restrict__ out) {
  const int t = blockIdx.x;
  const int c = threadIdx.x << 2;
  const int r0 = rowmap[2 * t], r1 = rowmap[2 * t + 1];
  const float g0 = tok_gate[2 * t], g1 = tok_gate[2 * t + 1];
  const ushort4 a = *reinterpret_cast<const ushort4*>(y + (size_t)r0 * HID + c);
  const ushort4 b = *reinterpret_cast<const ushort4*>(y + (size_t)r1 * HID + c);
  float4 o;
  o.x = g0 * bf2f(a.x) + g1 * bf2f(b.x);
  o.y = g0 * bf2f(a.y) + g1 * bf2f(b.y);
  o.z = g0 * bf2f(a.z) + g1 * bf2f(b.z);
  o.w = g0 * bf2f(a.w) + g1 * bf2f(b.w);
  *reinterpret_cast<float4*>(out + (size_t)t * HID + c) = o;
}

extern "C" void kernel_launch(void* const* d_in, const int* in_sizes, int n_in,
                              void* d_out, int out_size, void* d_ws, size_t ws_size,
                              hipStream_t stream) {
  const float* x  = (const float*)d_in[0]; // [8192][1024]
  const float* wr = (const float*)d_in[1]; // [1024][8]
  const float* w1 = (const float*)d_in[2]; // [8][1024][4096]
  const float* w2 = (const float*)d_in[3]; // [8][2048][1024]
  float* out = (float*)d_out;              // [8192][1024] fp32

  char* w = (char*)d_ws;
  int*   hdr        = (int*)w;
  int*   tok_idx    = (int*)(w + 1024);
  float* tok_gate   = (float*)(w + 1024 + 65536);
  int*   rowmap     = (int*)(w + 1024 + 2 * 65536);
  int*   bucket_tok = (int*)(w + 1024 + 3 * 65536);
  const size_t R1 = 524288;
  unsigned short* xb  = (unsigned short*)(w + R1);
  unsigned short* w1i = (unsigned short*)(w + R1 + 16777216);
  unsigned short* w2t = (unsigned short*)(w + R1);             // overlay
  unsigned short* yb  = (unsigned short*)(w + R1 + 33554432);  // overlay
  unsigned short* act = (unsigned short*)(w + R1 + 83886080);

  hipMemsetAsync(bucket_tok, 0, MAXPAD * sizeof(int), stream); // pad rows -> token 0

  k_router<<<T_TOK / 8, 512, 0, stream>>>(x, wr, tok_idx, tok_gate);
  k_count<<<1, 256, 0, stream>>>(tok_idx, hdr);
  k_scatter<<<(2 * T_TOK) / 256, 256, 0, stream>>>(tok_idx, hdr, bucket_tok, rowmap);
  k_cvt_x<<<(T_TOK * HID / 4) / 256, 256, 0, stream>>>(x, xb);
  k_cvtT<<<dim3(4096 / 64, 1024 / 64, 8), 256, 0, stream>>>(w1, w1i, 1024, 4096, 1);
  k_gemm1<<<dim3(16, MT1), 512, 0, stream>>>(xb, w1i, bucket_tok, hdr, act);
  k_cvtT<<<dim3(1024 / 64, 2048 / 64, 8), 256, 0, stream>>>(w2, w2t, 2048, 1024, 0);
  k_gemm2<<<dim3(8, MT1), 512, 0, stream>>>(act, w2t, hdr, yb);
  k_combine<<<T_TOK, 256, 0, stream>>>(yb, rowmap, tok_gate, out);
}